// Round 5
// baseline (511.266 us; speedup 1.0000x reference)
//
#include <hip/hip_runtime.h>
#include <hip/hip_bf16.h>

#define T_SEQ 4096
#define HIDDEN 2560
#define NH 8
#define NKV 4
#define HD 256
#define WINDOW 1024
#define SM_SCALE 0.0625f

typedef __bf16 bf16x8 __attribute__((ext_vector_type(8)));
typedef float f32x4 __attribute__((ext_vector_type(4)));
typedef __hip_bfloat16 bf16;

#define GLOAD_LDS(g, l) \
  __builtin_amdgcn_global_load_lds((const __attribute__((address_space(1))) void*)(g), \
                                   (__attribute__((address_space(3))) void*)(l), 16, 0, 0)

// ---------- fp32 -> bf16 elementwise convert (8 elems/thread) ----------
__global__ __launch_bounds__(256) void k_f2b(
    const float* __restrict__ src, bf16* __restrict__ dst)
{
  const size_t i = (size_t)blockIdx.x * 256 + threadIdx.x;
  const float4 a = ((const float4*)src)[i * 2];
  const float4 b = ((const float4*)src)[i * 2 + 1];
  bf16 tmp[8];
  tmp[0] = __float2bfloat16(a.x); tmp[1] = __float2bfloat16(a.y);
  tmp[2] = __float2bfloat16(a.z); tmp[3] = __float2bfloat16(a.w);
  tmp[4] = __float2bfloat16(b.x); tmp[5] = __float2bfloat16(b.y);
  tmp[6] = __float2bfloat16(b.z); tmp[7] = __float2bfloat16(b.w);
  *(bf16x8*)(dst + i * 8) = *(bf16x8*)tmp;
}

// ---------- fp32 src -> bf16 dst 64x64-tile transpose: dst[c][r] = (bf16)src[r][c] ----------
__global__ __launch_bounds__(256) void k_transpose_f2b(
    const float* __restrict__ src, bf16* __restrict__ dst, int srs, int drs)
{
  __shared__ bf16 t[64 * 72];  // +8 pad breaks bank conflicts on transposed read
  const int tid = threadIdx.x;
  const int c0 = blockIdx.x * 64;
  const int r0 = blockIdx.y * 64;
  const int rr = tid >> 3;
  const int cc = (tid & 7) * 8;
#pragma unroll
  for (int p = 0; p < 2; ++p) {
    const float* sp = src + (size_t)(r0 + p * 32 + rr) * srs + c0 + cc;
    const float4 a = *(const float4*)sp;
    const float4 b = *(const float4*)(sp + 4);
    bf16* tp = &t[(p * 32 + rr) * 72 + cc];
    tp[0] = __float2bfloat16(a.x); tp[1] = __float2bfloat16(a.y);
    tp[2] = __float2bfloat16(a.z); tp[3] = __float2bfloat16(a.w);
    tp[4] = __float2bfloat16(b.x); tp[5] = __float2bfloat16(b.y);
    tp[6] = __float2bfloat16(b.z); tp[7] = __float2bfloat16(b.w);
  }
  __syncthreads();
#pragma unroll
  for (int p = 0; p < 2; ++p) {
    const int n = p * 32 + rr;
    bf16x8 v;
#pragma unroll
    for (int i = 0; i < 8; ++i) v[i] = ((const __bf16*)t)[(cc + i) * 72 + n];
    *(bf16x8*)(dst + (size_t)(c0 + n) * drs + r0 + cc) = v;
  }
}

// ---------- bf16 64x64-tile transpose (for V): dst[c][r] = src[r][c] ----------
__global__ __launch_bounds__(256) void k_transpose(
    const bf16* __restrict__ src, bf16* __restrict__ dst,
    int srs, int drs, long src_zoff, long dst_zoff)
{
  __shared__ bf16 t[64 * 72];
  src += (size_t)blockIdx.z * src_zoff;
  dst += (size_t)blockIdx.z * dst_zoff;
  const int tid = threadIdx.x;
  const int c0 = blockIdx.x * 64;
  const int r0 = blockIdx.y * 64;
  const int rr = tid >> 3;
  const int cc = (tid & 7) * 8;
#pragma unroll
  for (int p = 0; p < 2; ++p) {
    bf16x8 v = *(const bf16x8*)(src + (size_t)(r0 + p * 32 + rr) * srs + c0 + cc);
    *(bf16x8*)(&t[(p * 32 + rr) * 72 + cc]) = v;
  }
  __syncthreads();
#pragma unroll
  for (int p = 0; p < 2; ++p) {
    const int n = p * 32 + rr;
    bf16x8 v;
#pragma unroll
    for (int i = 0; i < 8; ++i) v[i] = ((const __bf16*)t)[(cc + i) * 72 + n];
    *(bf16x8*)(dst + (size_t)(c0 + n) * drs + r0 + cc) = v;
  }
}

// ---------- m97-style bf16 GEMM: C[M][N] = A[M][K] * Bt[N][K]^T ----------
// OutT: bf16 for intermediates, float for the final projection (d_out is fp32!)
template <typename OutT>
__global__ __launch_bounds__(256) void k_gemm_bt(
    const bf16* __restrict__ A, const bf16* __restrict__ Bt,
    OutT* __restrict__ C, int M, int N, int K)
{
  __shared__ bf16 As[128 * 32];
  __shared__ bf16 Bs[128 * 32];
  const int tid = threadIdx.x;
  const int wave = tid >> 6;
  const int lane = tid & 63;
  const int l16 = lane & 15;
  const int quad = lane >> 4;
  const int m0 = blockIdx.y * 128;
  const int n0 = blockIdx.x * 128;
  const int wm = (wave >> 1) * 64;
  const int wn = (wave & 1) * 64;
  const int srow = tid >> 2;          // 0..63
  const int scol = (tid & 3) * 8;     // 0,8,16,24

  f32x4 acc[4][4] = {};

  for (int k0 = 0; k0 < K; k0 += 32) {
    const bf16* ag0 = A + (size_t)(m0 + srow) * K + k0 + scol;
    const bf16* bg0 = Bt + (size_t)(n0 + srow) * K + k0 + scol;
    char* al = (char*)As + wave * 1024;   // wave-uniform LDS base (HW adds lane*16)
    char* bl = (char*)Bs + wave * 1024;
    GLOAD_LDS(ag0, al);
    GLOAD_LDS(ag0 + (size_t)64 * K, al + 4096);
    GLOAD_LDS(bg0, bl);
    GLOAD_LDS(bg0 + (size_t)64 * K, bl + 4096);
    __syncthreads();
    bf16x8 af[4], bfr[4];
#pragma unroll
    for (int i = 0; i < 4; ++i)
      af[i] = *(const bf16x8*)(As + (wm + i * 16 + l16) * 32 + quad * 8);
#pragma unroll
    for (int i = 0; i < 4; ++i)
      bfr[i] = *(const bf16x8*)(Bs + (wn + i * 16 + l16) * 32 + quad * 8);
#pragma unroll
    for (int mi = 0; mi < 4; ++mi)
#pragma unroll
      for (int ni = 0; ni < 4; ++ni)
        acc[mi][ni] = __builtin_amdgcn_mfma_f32_16x16x32_bf16(af[mi], bfr[ni], acc[mi][ni], 0, 0, 0);
    __syncthreads();
  }
#pragma unroll
  for (int mi = 0; mi < 4; ++mi)
#pragma unroll
    for (int ni = 0; ni < 4; ++ni) {
      const int col = n0 + wn + ni * 16 + l16;
#pragma unroll
      for (int r = 0; r < 4; ++r) {
        const int row = m0 + wm + mi * 16 + quad * 4 + r;  // C/D: row=quad*4+reg, col=lane&15
        if constexpr (__is_same(OutT, float))
          C[(size_t)row * N + col] = acc[mi][ni][r];
        else
          C[(size_t)row * N + col] = __float2bfloat16(acc[mi][ni][r]);
      }
    }
}

// ---------- RMSNorm (fp32) + RoPE for q (slots 0..7) and k (slots 8..11) ----------
__global__ __launch_bounds__(64) void k_norm_rope(
    const bf16* __restrict__ qkv, const int* __restrict__ positions,
    const float* __restrict__ qw, const float* __restrict__ kw,
    bf16* __restrict__ q_r, bf16* __restrict__ k_r)
{
  const int t = blockIdx.x;
  const int slot = blockIdx.y;
  const int lane = threadIdx.x;
  const bf16* base = qkv + (size_t)t * 4096 + slot * 256;
  float x[4];
#pragma unroll
  for (int i = 0; i < 4; ++i) x[i] = __bfloat162float(base[lane + 64 * i]);
  float ss = x[0] * x[0] + x[1] * x[1] + x[2] * x[2] + x[3] * x[3];
#pragma unroll
  for (int off = 1; off < 64; off <<= 1) ss += __shfl_xor(ss, off, 64);
  const float rn = rsqrtf(ss * (1.0f / 256.0f) + 1e-6f);
  const float* w = (slot < 8) ? qw : kw;
  float nv[4];
#pragma unroll
  for (int i = 0; i < 4; ++i)
    nv[i] = x[i] * rn * (1.0f + w[lane + 64 * i]);
  // RoPE: dim pairs (d, d+128); thread's dims: lane, lane+64, lane+128, lane+192
  const float p = (float)positions[t];
  const float C_LOG2_10K_128 = 13.287712379549449f / 128.0f;
  const float f0 = p * exp2f(-(float)lane * C_LOG2_10K_128);
  const float f1 = p * exp2f(-(float)(lane + 64) * C_LOG2_10K_128);
  const float c0 = cosf(f0), s0 = sinf(f0);
  const float c1 = cosf(f1), s1 = sinf(f1);
  const float o0 = nv[0] * c0 - nv[2] * s0;
  const float o2 = nv[2] * c0 + nv[0] * s0;
  const float o1 = nv[1] * c1 - nv[3] * s1;
  const float o3 = nv[3] * c1 + nv[1] * s1;
  bf16* dst = (slot < 8) ? (q_r + ((size_t)slot * T_SEQ + t) * 256)
                         : (k_r + ((size_t)(slot - 8) * T_SEQ + t) * 256);
  dst[lane]       = __float2bfloat16(o0);
  dst[lane + 64]  = __float2bfloat16(o1);
  dst[lane + 128] = __float2bfloat16(o2);
  dst[lane + 192] = __float2bfloat16(o3);
}

// ---------- flash attention, sliding window, GQA ----------
// q_r [8][T][256], k_r [4][T][256], vt [4][256][T], attn [T][2048]
__global__ __launch_bounds__(256) void k_attn(
    const bf16* __restrict__ q_r, const bf16* __restrict__ k_r,
    const bf16* __restrict__ vt, bf16* __restrict__ attn)
{
  __shared__ bf16 Ks[32 * 256];    // [key][d]
  __shared__ bf16 Vts[256 * 32];   // [d][key]
  __shared__ bf16 Ps[4 * 16 * 32]; // per-wave P: [16 q][32 key]
  const int tid = threadIdx.x;
  const int wave = tid >> 6;
  const int lane = tid & 63;
  const int l16 = lane & 15;
  const int quad = lane >> 4;
  const int q0 = blockIdx.x * 64;
  const int h = blockIdx.y;
  const int kh = h >> 1;

  // Q A-fragments stay in registers: A[m=lane&15][k=quad*8+j], 8 k-steps of 32
  bf16x8 qf[8];
  {
    const bf16* qb = q_r + ((size_t)h * T_SEQ + q0 + wave * 16 + l16) * HD + quad * 8;
#pragma unroll
    for (int s = 0; s < 8; ++s) qf[s] = *(const bf16x8*)(qb + s * 32);
  }
  f32x4 O[16] = {};
  float mrow[4], lrow[4];
#pragma unroll
  for (int r = 0; r < 4; ++r) { mrow[r] = -1e30f; lrow[r] = 0.f; }

  const int jstart = ((q0 > 1023) ? (q0 - 1023) : 0) & ~31;
  const int jlast = q0 + 32;
  for (int j0 = jstart; j0 <= jlast; j0 += 32) {
    __syncthreads();  // prior tile's LDS reads drained before restage
    {
      const bf16* kg = k_r + ((size_t)kh * T_SEQ + j0 + (tid >> 5)) * HD + (tid & 31) * 8;
      const bf16* vg = vt + ((size_t)kh * HD + (tid >> 2)) * T_SEQ + j0 + (tid & 3) * 8;
      char* kl = (char*)Ks + wave * 1024;
      char* vl = (char*)Vts + wave * 1024;
#pragma unroll
      for (int p = 0; p < 4; ++p) {
        GLOAD_LDS(kg + (size_t)p * 8 * HD, kl + p * 4096);
        GLOAD_LDS(vg + (size_t)p * 64 * T_SEQ, vl + p * 4096);
      }
    }
    __syncthreads();  // staged data visible (barrier drains vmcnt)

    // S = Q K^T  (16 q x 32 keys per wave)
    f32x4 sa0 = {}, sa1 = {};
#pragma unroll
    for (int s = 0; s < 8; ++s) {
      bf16x8 kf0 = *(const bf16x8*)(Ks + l16 * HD + s * 32 + quad * 8);
      bf16x8 kf1 = *(const bf16x8*)(Ks + (16 + l16) * HD + s * 32 + quad * 8);
      sa0 = __builtin_amdgcn_mfma_f32_16x16x32_bf16(qf[s], kf0, sa0, 0, 0, 0);
      sa1 = __builtin_amdgcn_mfma_f32_16x16x32_bf16(qf[s], kf1, sa1, 0, 0, 0);
    }
    // online softmax per row (row = quad*4 + r); p zeroed explicitly for masked keys
#pragma unroll
    for (int r = 0; r < 4; ++r) {
      const int i = q0 + wave * 16 + quad * 4 + r;
      const int ja = j0 + l16;
      const int jb = ja + 16;
      const bool va = (ja <= i) && (i - ja < WINDOW);
      const bool vb = (jb <= i) && (i - jb < WINDOW);
      const float s0 = va ? sa0[r] * SM_SCALE : -1e30f;
      const float s1 = vb ? sa1[r] * SM_SCALE : -1e30f;
      float mx = fmaxf(s0, s1);
#pragma unroll
      for (int off = 1; off < 16; off <<= 1) mx = fmaxf(mx, __shfl_xor(mx, off, 64));
      const float mnew = fmaxf(mrow[r], mx);
      const float alpha = __expf(mrow[r] - mnew);
      const float p0 = va ? __expf(s0 - mnew) : 0.0f;
      const float p1 = vb ? __expf(s1 - mnew) : 0.0f;
      float rs = p0 + p1;
#pragma unroll
      for (int off = 1; off < 16; off <<= 1) rs += __shfl_xor(rs, off, 64);
      lrow[r] = lrow[r] * alpha + rs;
      mrow[r] = mnew;
#pragma unroll
      for (int n = 0; n < 16; ++n) O[n][r] *= alpha;
      Ps[wave * 512 + (quad * 4 + r) * 32 + l16]      = __float2bfloat16(p0);
      Ps[wave * 512 + (quad * 4 + r) * 32 + 16 + l16] = __float2bfloat16(p1);
    }
    // C-layout -> A-layout round trip through per-wave LDS (wave-internal only)
    asm volatile("s_waitcnt lgkmcnt(0)" ::: "memory");
    bf16x8 pf = *(const bf16x8*)(Ps + wave * 512 + l16 * 32 + quad * 8);
#pragma unroll
    for (int n = 0; n < 16; ++n) {
      bf16x8 vf = *(const bf16x8*)(Vts + (n * 16 + l16) * 32 + quad * 8);
      O[n] = __builtin_amdgcn_mfma_f32_16x16x32_bf16(pf, vf, O[n], 0, 0, 0);
    }
  }
  // epilogue: O /= l, write [T][H*D]
#pragma unroll
  for (int r = 0; r < 4; ++r) {
    const float inv = 1.0f / lrow[r];
    const size_t row = q0 + wave * 16 + quad * 4 + r;
#pragma unroll
    for (int n = 0; n < 16; ++n)
      attn[row * (NH * HD) + h * HD + n * 16 + l16] = __float2bfloat16(O[n][r] * inv);
  }
}

extern "C" void kernel_launch(void* const* d_in, const int* in_sizes, int n_in,
                              void* d_out, int out_size, void* d_ws, size_t ws_size,
                              hipStream_t stream)
{
  const float* x  = (const float*)d_in[0];
  const int* pos  = (const int*)d_in[1];
  const float* Wq = (const float*)d_in[2];
  const float* Wk = (const float*)d_in[3];
  const float* Wv = (const float*)d_in[4];
  const float* Wo = (const float*)d_in[5];
  const float* qw = (const float*)d_in[6];
  const float* kw = (const float*)d_in[7];
  float* out = (float*)d_out;   // reference output dtype is FP32

  char* ws = (char*)d_ws;
  size_t off = 0;
  bf16* Wqkv_t = (bf16*)(ws + off); off += (size_t)4096 * 2560 * 2;  // dead after GEMM1; reused as attn_b
  bf16* Wo_t   = (bf16*)(ws + off); off += (size_t)2560 * 2048 * 2;
  bf16* qkv_b  = (bf16*)(ws + off); off += (size_t)4096 * 4096 * 2;
  bf16* q_r    = (bf16*)(ws + off); off += (size_t)8 * 4096 * 256 * 2;
  bf16* k_r    = (bf16*)(ws + off); off += (size_t)4 * 4096 * 256 * 2;
  bf16* v_t    = (bf16*)(ws + off); off += (size_t)4 * 256 * 4096 * 2;
  bf16* attn_b = Wqkv_t;
  // x_bf16 (21 MB) aliases q_r (16.8 MB) + head of k_r: x_b dies at GEMM1,
  // q_r/k_r are written only after GEMM1 completes.
  bf16* x_b = q_r;
  if (ws_size < off) return;  // insufficient workspace -> fail loudly

  // fp32 -> bf16 conversions: x elementwise, weights fused into B^T transposes
  k_f2b<<<dim3((4096 * 2560) / (256 * 8)), 256, 0, stream>>>(x, x_b);
  k_transpose_f2b<<<dim3(32, 40), 256, 0, stream>>>(Wq, Wqkv_t, 2048, 2560);
  k_transpose_f2b<<<dim3(16, 40), 256, 0, stream>>>(Wk, Wqkv_t + (size_t)2048 * 2560, 1024, 2560);
  k_transpose_f2b<<<dim3(16, 40), 256, 0, stream>>>(Wv, Wqkv_t + (size_t)3072 * 2560, 1024, 2560);
  k_transpose_f2b<<<dim3(40, 32), 256, 0, stream>>>(Wo, Wo_t, 2560, 2048);
  // fused QKV projection: [4096,2560] x [2560,4096] -> [4096,4096] (bf16 out)
  k_gemm_bt<bf16><<<dim3(32, 32), 256, 0, stream>>>(x_b, Wqkv_t, qkv_b, 4096, 4096, 2560);
  // RMSNorm + RoPE for q,k (overwrites x_b region -- x_b is dead now)
  k_norm_rope<<<dim3(4096, 12), 64, 0, stream>>>(qkv_b, pos, qw, kw, q_r, k_r);
  // V transpose: qkv_b[t][3072+kh*256+d] -> v_t[kh][d][t]
  k_transpose<<<dim3(4, 64, 4), 256, 0, stream>>>(qkv_b + 3072, v_t, 4096, 4096, 256, (long)256 * 4096);
  // flash attention
  k_attn<<<dim3(64, 8), 256, 0, stream>>>(q_r, k_r, v_t, attn_b);
  // output projection: [4096,2048] x [2048,2560] -> out (FP32 out)
  k_gemm_bt<float><<<dim3(20, 32), 256, 0, stream>>>(attn_b, Wo_t, out, 4096, 2560, 2048);
}